// Round 3
// baseline (435.954 us; speedup 1.0000x reference)
//
#include <hip/hip_runtime.h>

// Fused GRU (Keras reset_after=True, relu) for MI355X — round 3.
// Block = 256 threads (4 waves) = ONE batch row. Grid = 512 = 2 blocks/CU.
//   Wave 0  : recurrence, wave-synchronous (no barriers inside steps).
//             Lane j owns unit j: rz,rr,rh dots via packed f32x2 FMAs,
//             U register-resident (96 f32x2), h broadcast from LDS (16 b128).
//   Waves 1-3: x-projection producers: X[16][192] = inp_chunk @ W + b0 via
//             bf16x3 MFMA (4 col-tiles/wave), double-buffered, ONE barrier
//             per 16-step chunk.
// 2 blocks/CU -> the co-resident block's waves hide the rec wave's latencies.

#define B_SZ   512
#define T_SZ   512
#define F_SZ   128
#define UN     64
#define G3     192
#define CHUNK  16
#define NCHUNK (T_SZ / CHUNK)
#define NCLS   10
#define XPAD   193

using short8 = __attribute__((ext_vector_type(8))) short;
using f32x4  = __attribute__((ext_vector_type(4))) float;
using f32x2  = __attribute__((ext_vector_type(2))) float;

__device__ __forceinline__ unsigned short f2bf_rn(float f) {
    unsigned int u = __float_as_uint(f);
    unsigned int r = u + 0x7FFFu + ((u >> 16) & 1u);
    return (unsigned short)(r >> 16);
}
__device__ __forceinline__ float bf2f(unsigned short s) {
    return __uint_as_float(((unsigned int)s) << 16);
}
__device__ __forceinline__ float sigmoidf_(float x) {
    return 1.0f / (1.0f + __expf(-x));
}
__device__ __forceinline__ f32x2 fma2(f32x2 a, f32x2 b, f32x2 c) {
#if __has_builtin(__builtin_elementwise_fma)
    return __builtin_elementwise_fma(a, b, c);   // -> v_pk_fma_f32
#else
    f32x2 r; r.x = fmaf(a.x, b.x, c.x); r.y = fmaf(a.y, b.y, c.y); return r;
#endif
}
#define WAVE_SYNC() asm volatile("s_waitcnt lgkmcnt(0)" ::: "memory")

__global__ __launch_bounds__(256, 2)
void gru_fused3(const float* __restrict__ inp,
                const float* __restrict__ W,
                const float* __restrict__ U,
                const float* __restrict__ bias,
                const float* __restrict__ W1,
                const float* __restrict__ b1,
                const float* __restrict__ W2,
                const float* __restrict__ b2,
                float* __restrict__ out)
{
    const int tid  = threadIdx.x;
    const int wave = tid >> 6;
    const int lane = tid & 63;
    const int l15  = lane & 15;
    const int l4   = lane >> 4;
    const int row  = blockIdx.x;

    __shared__ __align__(16) float Xb[2][CHUNK][XPAD];
    __shared__ __align__(16) float hb[UN];
    __shared__ __align__(16) float sc[UN];
    __shared__ float lg[NCLS];

    short8 wfh[4][4], wfl[4][4];
    float  b0c[4];
    f32x2 uz[32], ur[32], uh[32];
    float brz = 0.f, brr = 0.f, brh = 0.f;
    float h = 0.f;

    if (wave != 0) {
        const int pw = wave - 1;
        #pragma unroll
        for (int t = 0; t < 4; ++t) {
            const int col = 16 * (4 * pw + t) + l15;
            b0c[t] = bias[col];
            #pragma unroll
            for (int kt = 0; kt < 4; ++kt) {
                #pragma unroll
                for (int e = 0; e < 8; ++e) {
                    float w = W[(32 * kt + 8 * l4 + e) * G3 + col];
                    unsigned short hi = f2bf_rn(w);
                    unsigned short lo = f2bf_rn(w - bf2f(hi));
                    wfh[t][kt][e] = (short)hi;
                    wfl[t][kt][e] = (short)lo;
                }
            }
        }
    } else {
        #pragma unroll
        for (int k2 = 0; k2 < 32; ++k2) {
            uz[k2] = (f32x2){U[(2 * k2) * G3 + lane],       U[(2 * k2 + 1) * G3 + lane]};
            ur[k2] = (f32x2){U[(2 * k2) * G3 + 64 + lane],  U[(2 * k2 + 1) * G3 + 64 + lane]};
            uh[k2] = (f32x2){U[(2 * k2) * G3 + 128 + lane], U[(2 * k2 + 1) * G3 + 128 + lane]};
        }
        brz = bias[G3 + lane];
        brr = bias[G3 + 64 + lane];
        brh = bias[G3 + 128 + lane];
        hb[lane] = 0.f;
        WAVE_SYNC();
    }

    // prologue: stage chunk 0
    if (wave != 0) {
        const int pw = wave - 1;
        const float* ap = inp + (size_t)row * T_SZ * F_SZ + (size_t)l15 * F_SZ + 8 * l4;
        f32x4 acc[4];
        #pragma unroll
        for (int t = 0; t < 4; ++t) acc[t] = (f32x4){0.f, 0.f, 0.f, 0.f};
        #pragma unroll
        for (int kt = 0; kt < 4; ++kt) {
            f32x4 v0 = *(const f32x4*)(ap + 32 * kt);
            f32x4 v1 = *(const f32x4*)(ap + 32 * kt + 4);
            float av[8] = {v0[0], v0[1], v0[2], v0[3], v1[0], v1[1], v1[2], v1[3]};
            short8 ah8, al8;
            #pragma unroll
            for (int e = 0; e < 8; ++e) {
                unsigned short hi = f2bf_rn(av[e]);
                unsigned short lo = f2bf_rn(av[e] - bf2f(hi));
                ah8[e] = (short)hi; al8[e] = (short)lo;
            }
            #pragma unroll
            for (int t = 0; t < 4; ++t) {
                acc[t] = __builtin_amdgcn_mfma_f32_16x16x32_bf16(ah8, wfh[t][kt], acc[t], 0, 0, 0);
                acc[t] = __builtin_amdgcn_mfma_f32_16x16x32_bf16(al8, wfh[t][kt], acc[t], 0, 0, 0);
                acc[t] = __builtin_amdgcn_mfma_f32_16x16x32_bf16(ah8, wfl[t][kt], acc[t], 0, 0, 0);
            }
        }
        #pragma unroll
        for (int t = 0; t < 4; ++t) {
            const int col = 16 * (4 * pw + t) + l15;
            #pragma unroll
            for (int q = 0; q < 4; ++q)
                Xb[0][4 * l4 + q][col] = acc[t][q] + b0c[t];
        }
    }
    __syncthreads();

    for (int c = 0; c < NCHUNK; ++c) {
        if (wave != 0) {
            if (c + 1 < NCHUNK) {
                const int pw  = wave - 1;
                const int buf = (c + 1) & 1;
                const float* ap = inp + (size_t)row * T_SZ * F_SZ
                                + (size_t)((c + 1) * CHUNK + l15) * F_SZ + 8 * l4;
                f32x4 acc[4];
                #pragma unroll
                for (int t = 0; t < 4; ++t) acc[t] = (f32x4){0.f, 0.f, 0.f, 0.f};
                #pragma unroll
                for (int kt = 0; kt < 4; ++kt) {
                    f32x4 v0 = *(const f32x4*)(ap + 32 * kt);
                    f32x4 v1 = *(const f32x4*)(ap + 32 * kt + 4);
                    float av[8] = {v0[0], v0[1], v0[2], v0[3], v1[0], v1[1], v1[2], v1[3]};
                    short8 ah8, al8;
                    #pragma unroll
                    for (int e = 0; e < 8; ++e) {
                        unsigned short hi = f2bf_rn(av[e]);
                        unsigned short lo = f2bf_rn(av[e] - bf2f(hi));
                        ah8[e] = (short)hi; al8[e] = (short)lo;
                    }
                    #pragma unroll
                    for (int t = 0; t < 4; ++t) {
                        acc[t] = __builtin_amdgcn_mfma_f32_16x16x32_bf16(ah8, wfh[t][kt], acc[t], 0, 0, 0);
                        acc[t] = __builtin_amdgcn_mfma_f32_16x16x32_bf16(al8, wfh[t][kt], acc[t], 0, 0, 0);
                        acc[t] = __builtin_amdgcn_mfma_f32_16x16x32_bf16(ah8, wfl[t][kt], acc[t], 0, 0, 0);
                    }
                }
                #pragma unroll
                for (int t = 0; t < 4; ++t) {
                    const int col = 16 * (4 * pw + t) + l15;
                    #pragma unroll
                    for (int q = 0; q < 4; ++q)
                        Xb[buf][4 * l4 + q][col] = acc[t][q] + b0c[t];
                }
            }
        } else {
            const int buf = c & 1;
            for (int s = 0; s < CHUNK; ++s) {
                const float xz = Xb[buf][s][lane];
                const float xr = Xb[buf][s][64 + lane];
                const float xh = Xb[buf][s][128 + lane];

                f32x2 az = (f32x2){0.f, 0.f}, ar = az, ah = az;
                #pragma unroll
                for (int kb = 0; kb < 16; ++kb) {
                    f32x4 hv = *(const f32x4*)&hb[4 * kb];
                    f32x2 p0 = (f32x2){hv[0], hv[1]};
                    f32x2 p1 = (f32x2){hv[2], hv[3]};
                    az = fma2(p0, uz[2 * kb], az);
                    ar = fma2(p0, ur[2 * kb], ar);
                    ah = fma2(p0, uh[2 * kb], ah);
                    az = fma2(p1, uz[2 * kb + 1], az);
                    ar = fma2(p1, ur[2 * kb + 1], ar);
                    ah = fma2(p1, uh[2 * kb + 1], ah);
                }
                float rz = az[0] + az[1] + brz;
                float rr = ar[0] + ar[1] + brr;
                float rh = ah[0] + ah[1] + brh;
                float z  = sigmoidf_(xz + rz);
                float rg = sigmoidf_(xr + rr);
                float hh = fmaxf(fmaf(rg, rh, xh), 0.f);
                h = fmaf(z, h - hh, hh);
                hb[lane] = h;
                WAVE_SYNC();
            }
        }
        __syncthreads();
    }

    if (wave == 0) {
        float a = b1[lane];
        #pragma unroll 8
        for (int k = 0; k < UN; ++k)
            a = fmaf(hb[k], W1[k * UN + lane], a);
        sc[lane] = fmaxf(a, 0.f);
        WAVE_SYNC();

        if (lane < NCLS) {
            float acc = b2[lane];
            #pragma unroll 8
            for (int k = 0; k < UN; ++k)
                acc = fmaf(sc[k], W2[k * NCLS + lane], acc);
            lg[lane] = acc;
        }
        WAVE_SYNC();
        if (lane < NCLS) {
            float m = lg[0];
            #pragma unroll
            for (int k = 1; k < NCLS; ++k) m = fmaxf(m, lg[k]);
            float ssum = 0.f;
            #pragma unroll
            for (int k = 0; k < NCLS; ++k) ssum += __expf(lg[k] - m);
            out[row * NCLS + lane] = __expf(lg[lane] - m) / ssum;
        }
    }
}

extern "C" void kernel_launch(void* const* d_in, const int* in_sizes, int n_in,
                              void* d_out, int out_size, void* d_ws, size_t ws_size,
                              hipStream_t stream) {
    const float* inp  = (const float*)d_in[0];
    const float* W    = (const float*)d_in[1];
    const float* U    = (const float*)d_in[2];
    const float* bias = (const float*)d_in[3];
    const float* W1   = (const float*)d_in[4];
    const float* b1   = (const float*)d_in[5];
    const float* W2   = (const float*)d_in[6];
    const float* b2   = (const float*)d_in[7];
    float* out = (float*)d_out;

    gru_fused3<<<B_SZ, 256, 0, stream>>>(inp, W, U, bias, W1, b1, W2, b2, out);
}